// Round 18
// baseline (104.492 us; speedup 1.0000x reference)
//
#include <hip/hip_runtime.h>

typedef _Float16 f16;
typedef _Float16 f16x2 __attribute__((ext_vector_type(2)));
typedef _Float16 f16x4 __attribute__((ext_vector_type(4)));
typedef _Float16 f16x8 __attribute__((ext_vector_type(8)));
typedef float f32x4 __attribute__((ext_vector_type(4)));

#define BB 4
#define CC 256
#define HH 128
#define WW 128
#define OWW 64
#define DD 4096     // 64*64
#define NPIX 16384  // 128*128
#define CP 320      // c-pitch: 640B = 5 cache lines, rows 128B-aligned, non-pow2

// Merged prep: blocks 0..15 weight frag images; 16..2063 src transpose
// (64c x 128px tiles, float4 reads); 2064..2575 feat transpose+split.
__global__ __launch_bounds__(256) void prep_all_k(const float* __restrict__ Wq,
                                                  const float* __restrict__ Wv,
                                                  const float* __restrict__ src,
                                                  const float* __restrict__ feat,
                                                  f16* __restrict__ wqh,
                                                  f16* __restrict__ wvh,
                                                  f16* __restrict__ wvl,
                                                  f16* __restrict__ srcT,
                                                  f16* __restrict__ fth,
                                                  f16* __restrict__ ftl) {
    __shared__ float L[64][129];
    int bigid = blockIdx.x;
    int t = threadIdx.x;
    if (bigid < 16) {
        int bb = bigid;
        bool isQ = (bb < 8);
        const float* W = isQ ? Wq : Wv;
        int tt = (bb & 7) * 256 + t;      // 0..2047
        int G = tt >> 8, o = tt & 255;
#pragma unroll
        for (int kk = 0; kk < 4; ++kk) {
            const float* wr = W + (size_t)o * CC + kk * 64 + G * 8;
            float4 a = *(const float4*)wr;
            float4 b2 = *(const float4*)(wr + 4);
            float v[8] = {a.x, a.y, a.z, a.w, b2.x, b2.y, b2.z, b2.w};
            f16x8 hv, lv;
#pragma unroll
            for (int e = 0; e < 8; ++e) {
                f16 hh = (f16)v[e];
                hv[e] = hh;
                lv[e] = (f16)(v[e] - (float)hh);
            }
            size_t idx = (size_t)(((kk * 8 + G) * 256) + o) * 8;
            if (isQ) {
                *(f16x8*)&wqh[idx] = hv;
            } else {
                *(f16x8*)&wvh[idx] = hv;
                *(f16x8*)&wvl[idx] = lv;
            }
        }
    } else if (bigid < 16 + 2048) {
        int bid = bigid - 16;
        int pxt = bid & 127, ct = (bid >> 7) & 3, b = bid >> 9;
        int c0 = ct * 64, px0 = pxt * 128;
        const float* S = src + ((size_t)b * CC + c0) * NPIX + px0;
#pragma unroll
        for (int i = 0; i < 8; ++i) {
            int idx = i * 256 + t;            // 0..2047
            int cl = idx >> 5, p4 = (idx & 31) * 4;
            *(float4*)&L[cl][p4] = *(const float4*)(S + (size_t)cl * NPIX + p4);
        }
        __syncthreads();
        f16* D = srcT + ((size_t)b * NPIX + px0) * CP + c0;
#pragma unroll
        for (int i = 0; i < 4; ++i) {
            int idx = i * 256 + t;            // 0..1023
            int pl = idx >> 3, cg = (idx & 7) * 8;
            f16x8 v;
#pragma unroll
            for (int e = 0; e < 8; ++e) v[e] = (f16)L[cg + e][pl];
            *(f16x8*)&D[(size_t)pl * CP + cg] = v;
        }
    } else {
        int bid = bigid - 16 - 2048;
        int dt = bid & 31, ct = (bid >> 5) & 3, b = bid >> 7;
        int c0 = ct * 64, d0 = dt * 128;
        const float* S = feat + ((size_t)b * CC + c0) * DD + d0;
#pragma unroll
        for (int i = 0; i < 8; ++i) {
            int idx = i * 256 + t;
            int cl = idx >> 5, p4 = (idx & 31) * 4;
            *(float4*)&L[cl][p4] = *(const float4*)(S + (size_t)cl * DD + p4);
        }
        __syncthreads();
        size_t base = ((size_t)b * DD + d0) * CP + c0;
#pragma unroll
        for (int i = 0; i < 4; ++i) {
            int idx = i * 256 + t;
            int dl = idx >> 3, cg = (idx & 7) * 8;
            f16x8 hv, lv;
#pragma unroll
            for (int e = 0; e < 8; ++e) {
                float x = L[cg + e][dl];
                f16 hh = (f16)x;
                hv[e] = hh;
                lv[e] = (f16)(x - (float)hh);
            }
            *(f16x8*)&fth[base + (size_t)dl * CP + cg] = hv;
            *(f16x8*)&ftl[base + (size_t)dl * CP + cg] = lv;
        }
    }
}

// Merged GEMM kernel (R13 structure — best measured): blocks 0..511 = qcdot;
// 512..767 = vc. 512 thr, wave tile 64x64 / 32x64x3.
__global__ __launch_bounds__(512, 2) void qv_k(const f16* __restrict__ srcT,
                                               const float* __restrict__ feat,
                                               const f16* __restrict__ wqh,
                                               const float* __restrict__ bq,
                                               float* __restrict__ dotp,
                                               const f16* __restrict__ fth,
                                               const f16* __restrict__ ftl,
                                               const f16* __restrict__ wvh,
                                               const f16* __restrict__ wvl,
                                               const float* __restrict__ bv,
                                               f16* __restrict__ vh) {
    int t = threadIdx.x;
    if (blockIdx.x < 512) {
        // ================= qcdot branch =================
        __shared__ __align__(16) f16 Fl[512 * 36];
        int bid = blockIdx.x;
        int b = bid >> 7;
        int hp = (bid >> 1) & 63;
        int wh = bid & 1;
        int h = hp * 2;
        int w0 = wh * 64;
        int x0 = wh * 32;
        int ybase = hp;

        {
            const float* fb = feat + (size_t)b * CC * DD;
            int o = t >> 1, yi = t & 1;
            int y = ybase + yi;
            const float* frow = fb + (size_t)o * DD + y * 64 + x0;
            f16* dst = &Fl[(o * 2 + yi) * 36];
            if (y < 64) {
#pragma unroll
                for (int k2 = 0; k2 < 8; ++k2) {
                    float4 f = *(const float4*)&frow[k2 * 4];
                    f16x4 hv = {(f16)f.x, (f16)f.y, (f16)f.z, (f16)f.w};
                    *(f16x4*)&dst[k2 * 4] = hv;
                }
                dst[32] = (x0 + 32 < 64) ? (f16)frow[32] : (f16)0.f;
            } else {
                f16x4 z = {0, 0, 0, 0};
#pragma unroll
                for (int k2 = 0; k2 < 8; ++k2) *(f16x4*)&dst[k2 * 4] = z;
                dst[32] = (f16)0.f;
            }
        }
        __syncthreads();

        int wv = t >> 6;
        int lane = t & 63;
        int g = lane >> 4;
        int col = lane & 15;
        int rh = wv >> 2;
        int o0 = (wv & 3) * 64;

        f32x4 acc[4][4];
#pragma unroll
        for (int mf = 0; mf < 4; ++mf)
#pragma unroll
            for (int nf = 0; nf < 4; ++nf) acc[mf][nf] = (f32x4){0.f, 0.f, 0.f, 0.f};

        const f16* sTw = srcT + ((size_t)b * NPIX + (size_t)(h + rh) * WW + w0) * CP;

#pragma unroll
        for (int kk = 0; kk < 4; ++kk) {
#pragma unroll
            for (int s = 0; s < 2; ++s) {
                int G = s * 4 + g;
                int cb = kk * 64 + G * 8;
                f16x8 af[4], bh[4];
#pragma unroll
                for (int mf = 0; mf < 4; ++mf)
                    af[mf] = *(const f16x8*)&sTw[(size_t)(mf * 16 + col) * CP + cb];
#pragma unroll
                for (int nf = 0; nf < 4; ++nf) {
                    size_t idx = (size_t)(((kk * 8 + G) * 256) + o0 + nf * 16 + col) * 8;
                    bh[nf] = *(const f16x8*)&wqh[idx];
                }
#pragma unroll
                for (int mf = 0; mf < 4; ++mf)
#pragma unroll
                    for (int nf = 0; nf < 4; ++nf)
                        acc[mf][nf] = __builtin_amdgcn_mfma_f32_16x16x32_f16(af[mf], bh[nf], acc[mf][nf], 0, 0, 0);
            }
        }

        int i0 = rh ? 2 : 1;
        float bqv[4];
#pragma unroll
        for (int nf = 0; nf < 4; ++nf) bqv[nf] = bq[o0 + nf * 16 + col];

        float bins[4][2][3];
#pragma unroll
        for (int nf = 0; nf < 4; ++nf)
#pragma unroll
            for (int ii = 0; ii < 2; ++ii)
#pragma unroll
                for (int j = 0; j < 3; ++j) bins[nf][ii][j] = 0.f;

#pragma unroll
        for (int mf = 0; mf < 4; ++mf) {
            int X = mf * 8 + g * 2;
#pragma unroll
            for (int ii = 0; ii < 2; ++ii) {
                if (ii == 1 && rh == 0) continue;
#pragma unroll
                for (int nf = 0; nf < 4; ++nf) {
                    int o = o0 + nf * 16 + col;
                    const f16* fr = &Fl[(o * 2 + ii) * 36];
                    f16x2 lh = *(const f16x2*)&fr[X];
                    float lo = (float)lh[0], hi = (float)lh[1];
                    float s2 = (float)fr[X + 2];
                    float qv0 = acc[mf][nf][0] + bqv[nf];
                    float qv1 = acc[mf][nf][1] + bqv[nf];
                    float qv2 = acc[mf][nf][2] + bqv[nf];
                    float qv3 = acc[mf][nf][3] + bqv[nf];
                    bins[nf][ii][1] += qv0 * lo + qv2 * hi;
                    bins[nf][ii][2] += qv1 * lo + qv3 * hi;
                    bins[nf][ii][0] += qv1 * hi + qv3 * s2;
                }
            }
        }

#pragma unroll
        for (int m = 16; m <= 32; m <<= 1)
#pragma unroll
            for (int nf = 0; nf < 4; ++nf)
#pragma unroll
                for (int ii = 0; ii < 2; ++ii) {
                    if (ii == 1 && rh == 0) continue;
#pragma unroll
                    for (int j = 0; j < 3; ++j)
                        bins[nf][ii][j] += __shfl_xor(bins[nf][ii][j], m, 64);
                }

        if (g == 0) {
            float* dslot = dotp + (size_t)(bid & 127) * (9 * BB * CC);
#pragma unroll
            for (int nf = 0; nf < 4; ++nf) {
                int bc = b * CC + o0 + nf * 16 + col;
                dslot[(i0 * 3 + 0) * (BB * CC) + bc] = bins[nf][0][0];
                dslot[(i0 * 3 + 1) * (BB * CC) + bc] = bins[nf][0][1];
                dslot[(i0 * 3 + 2) * (BB * CC) + bc] = bins[nf][0][2];
                if (rh) {
                    dslot[0 * (BB * CC) + bc] = bins[nf][1][0];
                    dslot[1 * (BB * CC) + bc] = bins[nf][1][1];
                    dslot[2 * (BB * CC) + bc] = bins[nf][1][2];
                }
            }
        }
    } else {
        // ================= vc branch =================
        int bid = blockIdx.x - 512;
        int b = bid >> 6;
        int rest = bid & 63;
        int ot = rest >> 4;
        int dt = rest & 15;

        int wv = t >> 6;
        int wm = wv >> 2;
        int wn = wv & 3;
        int lane = t & 63;
        int g = lane >> 4;
        int col = lane & 15;

        int o_w = ot * 64 + wm * 32;
        int d_w = dt * 256 + wn * 64;

        f32x4 acc[2][4];
#pragma unroll
        for (int mf = 0; mf < 2; ++mf)
#pragma unroll
            for (int nf = 0; nf < 4; ++nf) acc[mf][nf] = (f32x4){0.f, 0.f, 0.f, 0.f};

        const f16* fthb = fth + (size_t)b * DD * CP;
        const f16* ftlb = ftl + (size_t)b * DD * CP;

#pragma unroll
        for (int kk = 0; kk < 4; ++kk) {
#pragma unroll
            for (int s = 0; s < 2; ++s) {
                int G = s * 4 + g;
                int cb = kk * 64 + G * 8;
                f16x8 bh[4], bl[4], ah[2], al[2];
#pragma unroll
                for (int nf = 0; nf < 4; ++nf) {
                    size_t off = (size_t)(d_w + nf * 16 + col) * CP + cb;
                    bh[nf] = *(const f16x8*)&fthb[off];
                    bl[nf] = *(const f16x8*)&ftlb[off];
                }
#pragma unroll
                for (int mf = 0; mf < 2; ++mf) {
                    size_t idx = (size_t)(((kk * 8 + G) * 256) + o_w + mf * 16 + col) * 8;
                    ah[mf] = *(const f16x8*)&wvh[idx];
                    al[mf] = *(const f16x8*)&wvl[idx];
                }
#pragma unroll
                for (int mf = 0; mf < 2; ++mf)
#pragma unroll
                    for (int nf = 0; nf < 4; ++nf)
                        acc[mf][nf] = __builtin_amdgcn_mfma_f32_16x16x32_f16(ah[mf], bh[nf], acc[mf][nf], 0, 0, 0);
#pragma unroll
                for (int mf = 0; mf < 2; ++mf)
#pragma unroll
                    for (int nf = 0; nf < 4; ++nf)
                        acc[mf][nf] = __builtin_amdgcn_mfma_f32_16x16x32_f16(al[mf], bh[nf], acc[mf][nf], 0, 0, 0);
#pragma unroll
                for (int mf = 0; mf < 2; ++mf)
#pragma unroll
                    for (int nf = 0; nf < 4; ++nf)
                        acc[mf][nf] = __builtin_amdgcn_mfma_f32_16x16x32_f16(ah[mf], bl[nf], acc[mf][nf], 0, 0, 0);
            }
        }

        f16* vb = vh + (size_t)b * CC * DD;
#pragma unroll
        for (int mf = 0; mf < 2; ++mf)
#pragma unroll
            for (int nf = 0; nf < 4; ++nf) {
#pragma unroll
                for (int r = 0; r < 4; ++r) {
                    int o = o_w + mf * 16 + g * 4 + r;
                    int d = d_w + nf * 16 + col;
                    vb[(size_t)o * DD + d] = (f16)(acc[mf][nf][r] + bv[o]);
                }
            }
    }
}

// Merged slot-reduction + softmax.
__global__ __launch_bounds__(288) void redsm_k(const float* __restrict__ dotp,
                                               float* __restrict__ A) {
    __shared__ float sl[9][33];
    int t = threadIdx.x;
    if (t < 288) {
        int k = t / 32, bcl = t % 32;
        int bc = blockIdx.x * 32 + bcl;
        float s = 0.f;
#pragma unroll 16
        for (int p = 0; p < 128; ++p)
            s += dotp[(size_t)p * (9 * BB * CC) + k * (BB * CC) + bc];
        sl[k][bcl] = s;
    }
    __syncthreads();
    if (t < 32) {
        int bc = blockIdx.x * 32 + t;
        float s[9];
        float m = -1e30f;
        const float sc = 1.f / 64.f;
#pragma unroll
        for (int k = 0; k < 9; ++k) { s[k] = sl[k][t] * sc; m = fmaxf(m, s[k]); }
        float sum = 0.f;
#pragma unroll
        for (int k = 0; k < 9; ++k) { s[k] = __expf(s[k] - m); sum += s[k]; }
        float inv = 1.f / sum;
#pragma unroll
        for (int k = 0; k < 9; ++k) A[(size_t)bc * 9 + k] = s[k] * inv;
    }
}

// out: each thread computes 4 consecutive w via float4.
__global__ __launch_bounds__(256) void out_k(const float* __restrict__ src,
                                             const f16* __restrict__ vh,
                                             const float* __restrict__ A,
                                             float* __restrict__ out) {
    __shared__ float Al[9];
    int bid = blockIdx.x;
    int bc = bid >> 4;
    int h0 = (bid & 15) << 3;
    int t = threadIdx.x;
    if (t < 9) Al[t] = A[(size_t)bc * 9 + t];
    __syncthreads();
    int h = h0 + (t >> 5);
    int a = t & 31;
    bool hodd = (h & 1) != 0;
    int iA = hodd ? 2 : 1;
    int yA = hodd ? ((h - 1) >> 1) : (h >> 1);
    int yB = (h + 1) >> 1;
    bool hasB = hodd && (yB < 64);

    const f16* vb = vh + (size_t)bc * DD;
    float s0 = 0.f, s1 = 0.f, s2 = 0.f, s3 = 0.f;
    {
        const f16* vr = vb + yA * OWW + 2 * a;
        f16x2 v01 = *(const f16x2*)vr;
        float V0 = (float)v01[0], V1 = (float)v01[1];
        float V2 = (2 * a + 2 < 64) ? (float)vr[2] : 0.f;
        float A0 = Al[iA * 3 + 0], A1 = Al[iA * 3 + 1], A2 = Al[iA * 3 + 2];
        s0 += A1 * V0;
        s1 += A0 * V1 + A2 * V0;
        s2 += A1 * V1;
        s3 += A0 * V2 + A2 * V1;
    }
    if (hasB) {
        const f16* vr = vb + yB * OWW + 2 * a;
        f16x2 v01 = *(const f16x2*)vr;
        float V0 = (float)v01[0], V1 = (float)v01[1];
        float V2 = (2 * a + 2 < 64) ? (float)vr[2] : 0.f;
        float A0 = Al[0], A1 = Al[1], A2 = Al[2];
        s0 += A1 * V0;
        s1 += A0 * V1 + A2 * V0;
        s2 += A1 * V1;
        s3 += A0 * V2 + A2 * V1;
    }
    size_t idx = (size_t)bc * NPIX + (size_t)h * WW + a * 4;
    float4 sv = *(const float4*)(src + idx);
    float4 o4;
    o4.x = s0 * sv.x; o4.y = s1 * sv.y; o4.z = s2 * sv.z; o4.w = s3 * sv.w;
    *(float4*)(out + idx) = o4;
}

extern "C" void kernel_launch(void* const* d_in, const int* in_sizes, int n_in,
                              void* d_out, int out_size, void* d_ws, size_t ws_size,
                              hipStream_t stream) {
    const float* feat = (const float*)d_in[0];
    const float* src  = (const float*)d_in[1];
    const float* Wq   = (const float*)d_in[2];
    const float* bq   = (const float*)d_in[3];
    const float* Wv   = (const float*)d_in[4];
    const float* bv   = (const float*)d_in[5];
    float* out = (float*)d_out;

    f16*   vh   = (f16*)d_ws;                                // 8.39MB
    float* dotp = (float*)(vh + (size_t)BB * CC * DD);       // 4.72MB
    float* A    = dotp + (size_t)128 * 9 * BB * CC;          // 36.9KB
    f16*   wqh  = (f16*)(A + (size_t)BB * CC * 9);           // 131KB
    f16*   wvh  = wqh + 65536;
    f16*   wvl  = wvh + 65536;
    f16*   srcT = wvl + 65536;                               // 41.9MB (CP=320)
    f16*   fth  = srcT + (size_t)BB * NPIX * CP;             // 10.5MB
    f16*   ftl  = fth + (size_t)BB * DD * CP;                // 10.5MB

    prep_all_k<<<16 + 2048 + 512, 256, 0, stream>>>(Wq, Wv, src, feat,
                                                    wqh, wvh, wvl, srcT, fth, ftl);
    qv_k<<<768, 512, 0, stream>>>(srcT, feat, wqh, bq, dotp,
                                  fth, ftl, wvh, wvl, bv, vh);
    redsm_k<<<BB * CC / 32, 288, 0, stream>>>(dotp, A);
    out_k<<<BB * CC * 16, 256, 0, stream>>>(src, vh, A, out);
}

// Round 20
// 96.515 us; speedup vs baseline: 1.0827x; 1.0827x over previous
//
#include <hip/hip_runtime.h>

typedef _Float16 f16;
typedef _Float16 f16x2 __attribute__((ext_vector_type(2)));
typedef _Float16 f16x4 __attribute__((ext_vector_type(4)));
typedef _Float16 f16x8 __attribute__((ext_vector_type(8)));
typedef float f32x4 __attribute__((ext_vector_type(4)));

#define BB 4
#define CC 256
#define HH 128
#define WW 128
#define OWW 64
#define DD 4096     // 64*64
#define NPIX 16384  // 128*128
#define CP 264      // padded c-pitch for transposed layouts (528B, non-pow2)

// Merged prep: blocks 0..15 weight frag images; 16..2063 src transpose
// (64c x 128px tiles, float4 reads); 2064..2575 feat transpose+split.
__global__ __launch_bounds__(256) void prep_all_k(const float* __restrict__ Wq,
                                                  const float* __restrict__ Wv,
                                                  const float* __restrict__ src,
                                                  const float* __restrict__ feat,
                                                  f16* __restrict__ wqh,
                                                  f16* __restrict__ wvh,
                                                  f16* __restrict__ wvl,
                                                  f16* __restrict__ srcT,
                                                  f16* __restrict__ fth,
                                                  f16* __restrict__ ftl) {
    __shared__ float L[64][129];
    int bigid = blockIdx.x;
    int t = threadIdx.x;
    if (bigid < 16) {
        int bb = bigid;
        bool isQ = (bb < 8);
        const float* W = isQ ? Wq : Wv;
        int tt = (bb & 7) * 256 + t;      // 0..2047
        int G = tt >> 8, o = tt & 255;
#pragma unroll
        for (int kk = 0; kk < 4; ++kk) {
            const float* wr = W + (size_t)o * CC + kk * 64 + G * 8;
            float4 a = *(const float4*)wr;
            float4 b2 = *(const float4*)(wr + 4);
            float v[8] = {a.x, a.y, a.z, a.w, b2.x, b2.y, b2.z, b2.w};
            f16x8 hv, lv;
#pragma unroll
            for (int e = 0; e < 8; ++e) {
                f16 hh = (f16)v[e];
                hv[e] = hh;
                lv[e] = (f16)(v[e] - (float)hh);
            }
            size_t idx = (size_t)(((kk * 8 + G) * 256) + o) * 8;
            if (isQ) {
                *(f16x8*)&wqh[idx] = hv;
            } else {
                *(f16x8*)&wvh[idx] = hv;
                *(f16x8*)&wvl[idx] = lv;
            }
        }
    } else if (bigid < 16 + 2048) {
        int bid = bigid - 16;
        int pxt = bid & 127, ct = (bid >> 7) & 3, b = bid >> 9;
        int c0 = ct * 64, px0 = pxt * 128;
        const float* S = src + ((size_t)b * CC + c0) * NPIX + px0;
#pragma unroll
        for (int i = 0; i < 8; ++i) {
            int idx = i * 256 + t;            // 0..2047
            int cl = idx >> 5, p4 = (idx & 31) * 4;
            *(float4*)&L[cl][p4] = *(const float4*)(S + (size_t)cl * NPIX + p4);
        }
        __syncthreads();
        f16* D = srcT + ((size_t)b * NPIX + px0) * CP + c0;
#pragma unroll
        for (int i = 0; i < 4; ++i) {
            int idx = i * 256 + t;            // 0..1023
            int pl = idx >> 3, cg = (idx & 7) * 8;
            f16x8 v;
#pragma unroll
            for (int e = 0; e < 8; ++e) v[e] = (f16)L[cg + e][pl];
            *(f16x8*)&D[(size_t)pl * CP + cg] = v;
        }
    } else {
        int bid = bigid - 16 - 2048;
        int dt = bid & 31, ct = (bid >> 5) & 3, b = bid >> 7;
        int c0 = ct * 64, d0 = dt * 128;
        const float* S = feat + ((size_t)b * CC + c0) * DD + d0;
#pragma unroll
        for (int i = 0; i < 8; ++i) {
            int idx = i * 256 + t;
            int cl = idx >> 5, p4 = (idx & 31) * 4;
            *(float4*)&L[cl][p4] = *(const float4*)(S + (size_t)cl * DD + p4);
        }
        __syncthreads();
        size_t base = ((size_t)b * DD + d0) * CP + c0;
#pragma unroll
        for (int i = 0; i < 4; ++i) {
            int idx = i * 256 + t;
            int dl = idx >> 3, cg = (idx & 7) * 8;
            f16x8 hv, lv;
#pragma unroll
            for (int e = 0; e < 8; ++e) {
                float x = L[cg + e][dl];
                f16 hh = (f16)x;
                hv[e] = hh;
                lv[e] = (f16)(x - (float)hh);
            }
            *(f16x8*)&fth[base + (size_t)dl * CP + cg] = hv;
            *(f16x8*)&ftl[base + (size_t)dl * CP + cg] = lv;
        }
    }
}

// Merged GEMM kernel: blocks 0..511 = qcdot (fused qc-GEMM + dot epilogue);
// blocks 512..767 = vc (v = Wv@feat split-f16 -> vh). Single-stage register
// set (compiler schedules loads); 512 thr.
__global__ __launch_bounds__(512, 2) void qv_k(const f16* __restrict__ srcT,
                                               const float* __restrict__ feat,
                                               const f16* __restrict__ wqh,
                                               const float* __restrict__ bq,
                                               float* __restrict__ dotp,
                                               const f16* __restrict__ fth,
                                               const f16* __restrict__ ftl,
                                               const f16* __restrict__ wvh,
                                               const f16* __restrict__ wvl,
                                               const float* __restrict__ bv,
                                               f16* __restrict__ vh) {
    int t = threadIdx.x;
    if (blockIdx.x < 512) {
        // ================= qcdot branch =================
        __shared__ __align__(16) f16 Fl[512 * 36];
        int bid = blockIdx.x;
        int b = bid >> 7;
        int hp = (bid >> 1) & 63;
        int wh = bid & 1;
        int h = hp * 2;
        int w0 = wh * 64;
        int x0 = wh * 32;
        int ybase = hp;

        {
            const float* fb = feat + (size_t)b * CC * DD;
            int o = t >> 1, yi = t & 1;
            int y = ybase + yi;
            const float* frow = fb + (size_t)o * DD + y * 64 + x0;
            f16* dst = &Fl[(o * 2 + yi) * 36];
            if (y < 64) {
#pragma unroll
                for (int k2 = 0; k2 < 8; ++k2) {
                    float4 f = *(const float4*)&frow[k2 * 4];
                    f16x4 hv = {(f16)f.x, (f16)f.y, (f16)f.z, (f16)f.w};
                    *(f16x4*)&dst[k2 * 4] = hv;
                }
                dst[32] = (x0 + 32 < 64) ? (f16)frow[32] : (f16)0.f;
            } else {
                f16x4 z = {0, 0, 0, 0};
#pragma unroll
                for (int k2 = 0; k2 < 8; ++k2) *(f16x4*)&dst[k2 * 4] = z;
                dst[32] = (f16)0.f;
            }
        }
        __syncthreads();

        int wv = t >> 6;
        int lane = t & 63;
        int g = lane >> 4;
        int col = lane & 15;
        int rh = wv >> 2;
        int o0 = (wv & 3) * 64;

        f32x4 acc[4][4];
#pragma unroll
        for (int mf = 0; mf < 4; ++mf)
#pragma unroll
            for (int nf = 0; nf < 4; ++nf) acc[mf][nf] = (f32x4){0.f, 0.f, 0.f, 0.f};

        const f16* sTw = srcT + ((size_t)b * NPIX + (size_t)(h + rh) * WW + w0) * CP;

#pragma unroll
        for (int kk = 0; kk < 4; ++kk) {
#pragma unroll
            for (int s = 0; s < 2; ++s) {
                int G = s * 4 + g;
                int cb = kk * 64 + G * 8;
                f16x8 af[4], bh[4];
#pragma unroll
                for (int mf = 0; mf < 4; ++mf)
                    af[mf] = *(const f16x8*)&sTw[(size_t)(mf * 16 + col) * CP + cb];
#pragma unroll
                for (int nf = 0; nf < 4; ++nf) {
                    size_t idx = (size_t)(((kk * 8 + G) * 256) + o0 + nf * 16 + col) * 8;
                    bh[nf] = *(const f16x8*)&wqh[idx];
                }
#pragma unroll
                for (int mf = 0; mf < 4; ++mf)
#pragma unroll
                    for (int nf = 0; nf < 4; ++nf)
                        acc[mf][nf] = __builtin_amdgcn_mfma_f32_16x16x32_f16(af[mf], bh[nf], acc[mf][nf], 0, 0, 0);
            }
        }

        int i0 = rh ? 2 : 1;
        float bqv[4];
#pragma unroll
        for (int nf = 0; nf < 4; ++nf) bqv[nf] = bq[o0 + nf * 16 + col];

        float bins[4][2][3];
#pragma unroll
        for (int nf = 0; nf < 4; ++nf)
#pragma unroll
            for (int ii = 0; ii < 2; ++ii)
#pragma unroll
                for (int j = 0; j < 3; ++j) bins[nf][ii][j] = 0.f;

#pragma unroll
        for (int mf = 0; mf < 4; ++mf) {
            int X = mf * 8 + g * 2;
#pragma unroll
            for (int ii = 0; ii < 2; ++ii) {
                if (ii == 1 && rh == 0) continue;
#pragma unroll
                for (int nf = 0; nf < 4; ++nf) {
                    int o = o0 + nf * 16 + col;
                    const f16* fr = &Fl[(o * 2 + ii) * 36];
                    f16x2 lh = *(const f16x2*)&fr[X];
                    float lo = (float)lh[0], hi = (float)lh[1];
                    float s2 = (float)fr[X + 2];
                    float qv0 = acc[mf][nf][0] + bqv[nf];
                    float qv1 = acc[mf][nf][1] + bqv[nf];
                    float qv2 = acc[mf][nf][2] + bqv[nf];
                    float qv3 = acc[mf][nf][3] + bqv[nf];
                    bins[nf][ii][1] += qv0 * lo + qv2 * hi;
                    bins[nf][ii][2] += qv1 * lo + qv3 * hi;
                    bins[nf][ii][0] += qv1 * hi + qv3 * s2;
                }
            }
        }

#pragma unroll
        for (int m = 16; m <= 32; m <<= 1)
#pragma unroll
            for (int nf = 0; nf < 4; ++nf)
#pragma unroll
                for (int ii = 0; ii < 2; ++ii) {
                    if (ii == 1 && rh == 0) continue;
#pragma unroll
                    for (int j = 0; j < 3; ++j)
                        bins[nf][ii][j] += __shfl_xor(bins[nf][ii][j], m, 64);
                }

        if (g == 0) {
            float* dslot = dotp + (size_t)(bid & 127) * (9 * BB * CC);
#pragma unroll
            for (int nf = 0; nf < 4; ++nf) {
                int bc = b * CC + o0 + nf * 16 + col;
                dslot[(i0 * 3 + 0) * (BB * CC) + bc] = bins[nf][0][0];
                dslot[(i0 * 3 + 1) * (BB * CC) + bc] = bins[nf][0][1];
                dslot[(i0 * 3 + 2) * (BB * CC) + bc] = bins[nf][0][2];
                if (rh) {
                    dslot[0 * (BB * CC) + bc] = bins[nf][1][0];
                    dslot[1 * (BB * CC) + bc] = bins[nf][1][1];
                    dslot[2 * (BB * CC) + bc] = bins[nf][1][2];
                }
            }
        }
    } else {
        // ================= vc branch =================
        int bid = blockIdx.x - 512;
        int b = bid >> 6;
        int rest = bid & 63;
        int ot = rest >> 4;
        int dt = rest & 15;

        int wv = t >> 6;
        int wm = wv >> 2;
        int wn = wv & 3;
        int lane = t & 63;
        int g = lane >> 4;
        int col = lane & 15;

        int o_w = ot * 64 + wm * 32;
        int d_w = dt * 256 + wn * 64;

        f32x4 acc[2][4];
#pragma unroll
        for (int mf = 0; mf < 2; ++mf)
#pragma unroll
            for (int nf = 0; nf < 4; ++nf) acc[mf][nf] = (f32x4){0.f, 0.f, 0.f, 0.f};

        const f16* fthb = fth + (size_t)b * DD * CP;
        const f16* ftlb = ftl + (size_t)b * DD * CP;

#pragma unroll
        for (int kk = 0; kk < 4; ++kk) {
#pragma unroll
            for (int s = 0; s < 2; ++s) {
                int G = s * 4 + g;
                int cb = kk * 64 + G * 8;
                f16x8 bh[4], bl[4], ah[2], al[2];
#pragma unroll
                for (int nf = 0; nf < 4; ++nf) {
                    size_t off = (size_t)(d_w + nf * 16 + col) * CP + cb;
                    bh[nf] = *(const f16x8*)&fthb[off];
                    bl[nf] = *(const f16x8*)&ftlb[off];
                }
#pragma unroll
                for (int mf = 0; mf < 2; ++mf) {
                    size_t idx = (size_t)(((kk * 8 + G) * 256) + o_w + mf * 16 + col) * 8;
                    ah[mf] = *(const f16x8*)&wvh[idx];
                    al[mf] = *(const f16x8*)&wvl[idx];
                }
#pragma unroll
                for (int mf = 0; mf < 2; ++mf)
#pragma unroll
                    for (int nf = 0; nf < 4; ++nf)
                        acc[mf][nf] = __builtin_amdgcn_mfma_f32_16x16x32_f16(ah[mf], bh[nf], acc[mf][nf], 0, 0, 0);
#pragma unroll
                for (int mf = 0; mf < 2; ++mf)
#pragma unroll
                    for (int nf = 0; nf < 4; ++nf)
                        acc[mf][nf] = __builtin_amdgcn_mfma_f32_16x16x32_f16(al[mf], bh[nf], acc[mf][nf], 0, 0, 0);
#pragma unroll
                for (int mf = 0; mf < 2; ++mf)
#pragma unroll
                    for (int nf = 0; nf < 4; ++nf)
                        acc[mf][nf] = __builtin_amdgcn_mfma_f32_16x16x32_f16(ah[mf], bl[nf], acc[mf][nf], 0, 0, 0);
            }
        }

        f16* vb = vh + (size_t)b * CC * DD;
#pragma unroll
        for (int mf = 0; mf < 2; ++mf)
#pragma unroll
            for (int nf = 0; nf < 4; ++nf) {
#pragma unroll
                for (int r = 0; r < 4; ++r) {
                    int o = o_w + mf * 16 + g * 4 + r;
                    int d = d_w + nf * 16 + col;
                    vb[(size_t)o * DD + d] = (f16)(acc[mf][nf][r] + bv[o]);
                }
            }
    }
}

// Merged slot-reduction + softmax.
__global__ __launch_bounds__(288) void redsm_k(const float* __restrict__ dotp,
                                               float* __restrict__ A) {
    __shared__ float sl[9][33];
    int t = threadIdx.x;
    if (t < 288) {
        int k = t / 32, bcl = t % 32;
        int bc = blockIdx.x * 32 + bcl;
        float s = 0.f;
#pragma unroll 16
        for (int p = 0; p < 128; ++p)
            s += dotp[(size_t)p * (9 * BB * CC) + k * (BB * CC) + bc];
        sl[k][bcl] = s;
    }
    __syncthreads();
    if (t < 32) {
        int bc = blockIdx.x * 32 + t;
        float s[9];
        float m = -1e30f;
        const float sc = 1.f / 64.f;
#pragma unroll
        for (int k = 0; k < 9; ++k) { s[k] = sl[k][t] * sc; m = fmaxf(m, s[k]); }
        float sum = 0.f;
#pragma unroll
        for (int k = 0; k < 9; ++k) { s[k] = __expf(s[k] - m); sum += s[k]; }
        float inv = 1.f / sum;
#pragma unroll
        for (int k = 0; k < 9; ++k) A[(size_t)bc * 9 + k] = s[k] * inv;
    }
}

// out: each thread computes 4 consecutive w via float4.
__global__ __launch_bounds__(256) void out_k(const float* __restrict__ src,
                                             const f16* __restrict__ vh,
                                             const float* __restrict__ A,
                                             float* __restrict__ out) {
    __shared__ float Al[9];
    int bid = blockIdx.x;
    int bc = bid >> 4;
    int h0 = (bid & 15) << 3;
    int t = threadIdx.x;
    if (t < 9) Al[t] = A[(size_t)bc * 9 + t];
    __syncthreads();
    int h = h0 + (t >> 5);
    int a = t & 31;
    bool hodd = (h & 1) != 0;
    int iA = hodd ? 2 : 1;
    int yA = hodd ? ((h - 1) >> 1) : (h >> 1);
    int yB = (h + 1) >> 1;
    bool hasB = hodd && (yB < 64);

    const f16* vb = vh + (size_t)bc * DD;
    float s0 = 0.f, s1 = 0.f, s2 = 0.f, s3 = 0.f;
    {
        const f16* vr = vb + yA * OWW + 2 * a;
        f16x2 v01 = *(const f16x2*)vr;
        float V0 = (float)v01[0], V1 = (float)v01[1];
        float V2 = (2 * a + 2 < 64) ? (float)vr[2] : 0.f;
        float A0 = Al[iA * 3 + 0], A1 = Al[iA * 3 + 1], A2 = Al[iA * 3 + 2];
        s0 += A1 * V0;
        s1 += A0 * V1 + A2 * V0;
        s2 += A1 * V1;
        s3 += A0 * V2 + A2 * V1;
    }
    if (hasB) {
        const f16* vr = vb + yB * OWW + 2 * a;
        f16x2 v01 = *(const f16x2*)vr;
        float V0 = (float)v01[0], V1 = (float)v01[1];
        float V2 = (2 * a + 2 < 64) ? (float)vr[2] : 0.f;
        float A0 = Al[0], A1 = Al[1], A2 = Al[2];
        s0 += A1 * V0;
        s1 += A0 * V1 + A2 * V0;
        s2 += A1 * V1;
        s3 += A0 * V2 + A2 * V1;
    }
    size_t idx = (size_t)bc * NPIX + (size_t)h * WW + a * 4;
    float4 sv = *(const float4*)(src + idx);
    float4 o4;
    o4.x = s0 * sv.x; o4.y = s1 * sv.y; o4.z = s2 * sv.z; o4.w = s3 * sv.w;
    *(float4*)(out + idx) = o4;
}

extern "C" void kernel_launch(void* const* d_in, const int* in_sizes, int n_in,
                              void* d_out, int out_size, void* d_ws, size_t ws_size,
                              hipStream_t stream) {
    const float* feat = (const float*)d_in[0];
    const float* src  = (const float*)d_in[1];
    const float* Wq   = (const float*)d_in[2];
    const float* bq   = (const float*)d_in[3];
    const float* Wv   = (const float*)d_in[4];
    const float* bv   = (const float*)d_in[5];
    float* out = (float*)d_out;

    f16*   vh   = (f16*)d_ws;                                // 8.4MB
    float* dotp = (float*)(vh + (size_t)BB * CC * DD);       // 4.7MB
    float* A    = dotp + (size_t)128 * 9 * BB * CC;          // 36.9KB
    f16*   wqh  = (f16*)(A + (size_t)BB * CC * 9);           // 131KB
    f16*   wvh  = wqh + 65536;
    f16*   wvl  = wvh + 65536;
    f16*   srcT = wvl + 65536;                               // 34.6MB
    f16*   fth  = srcT + (size_t)BB * NPIX * CP;             // 8.65MB
    f16*   ftl  = fth + (size_t)BB * DD * CP;                // 8.65MB

    prep_all_k<<<16 + 2048 + 512, 256, 0, stream>>>(Wq, Wv, src, feat,
                                                    wqh, wvh, wvl, srcT, fth, ftl);
    qv_k<<<768, 512, 0, stream>>>(srcT, feat, wqh, bq, dotp,
                                  fth, ftl, wvh, wvl, bv, vh);
    redsm_k<<<BB * CC / 32, 288, 0, stream>>>(dotp, A);
    out_k<<<BB * CC * 16, 256, 0, stream>>>(src, vh, A, out);
}